// Round 7
// baseline (85.526 us; speedup 1.0000x reference)
//
#include <hip/hip_runtime.h>
#include <math.h>

#define T_ 128
#define B_ 8
#define C_ 25000
#define W_ 4
#define NROWS (T_ * B_)          // 1024
#define NT4 (C_ / 4)             // 6250 quads/row; 6250 = 512*12 + 106
#define TAILQ (NT4 - 512 * 12)   // 106
#define SEQ_ELEMS (B_ * W_ * (T_ + 1))  // 4128

// workspace layout (bytes), all rows indexed orow = b*T_ + t
#define WS_DEN   0        // [1024] f64  sum(exp(x))
#define WS_M1    8192     // [1024] f32  row max
#define WS_I0    12288    // [1024] i32  argmax (first occurrence)
#define WS_TIED  16384    // [1024] i32  max duplicated (bitwise)
#define WS_T4V   20480    // [1024][4] f32  (phase-2 rows only)
#define WS_T4I   36864    // [1024][4] i32
#define WS_PCH   53248    // [8][128][4] u32 packed (parent<<16)|char, tie steps
#define WS_CNT   69632    // i32 block-completion counter

// Tie-exact comparator: value desc, index asc (matches lax.top_k tie rule).
__device__ __forceinline__ bool better(float av, int ai, float bv, int bi) {
  return (av > bv) || (av == bv && ai < bi);
}

__global__ __launch_bounds__(512, 8) void fused_kernel(
    const float* __restrict__ logits, char* __restrict__ ws,
    float* __restrict__ out) {
  double* d_den = (double*)(ws + WS_DEN);
  float* d_m1 = (float*)(ws + WS_M1);
  int* d_i0 = (int*)(ws + WS_I0);
  int* d_tied = (int*)(ws + WS_TIED);
  float* d_t4v = (float*)(ws + WS_T4V);
  int* d_t4i = (int*)(ws + WS_T4I);
  unsigned* pch_g = (unsigned*)(ws + WS_PCH);
  int* counter = (int*)(ws + WS_CNT);

  // LDS overlay: phase-2 (16 KB) and beam stage (29.3 KB) are temporally
  // disjoint within a block.
  __shared__ char smem[29312] __attribute__((aligned(16)));
  __shared__ float g_m1[8], g_m2[8];
  __shared__ int g_idx[8];
  __shared__ double g_sum[8];
  __shared__ int sh_phase2, sh_last;

  const int row = blockIdx.x;  // row = t*B + b (input layout [T,B,C])
  const int tid = threadIdx.x;
  const float4* __restrict__ x4 = (const float4*)(logits + (size_t)row * C_);

  // ---------------- phase 1: branchless row stats (no f64 libm!) ----------
  float m1 = -INFINITY, m2 = -INFINITY;
  int iq = 0, ij = 0;
  float s0 = 0.f, s1 = 0.f, s2 = 0.f, s3 = 0.f;

  auto consume = [&](const float4 q, int i) {
    { bool c = q.x > m1; m2 = __builtin_amdgcn_fmed3f(q.x, m1, m2);
      m1 = fmaxf(m1, q.x); iq = c ? i : iq; ij = c ? 0 : ij; s0 += __expf(q.x); }
    { bool c = q.y > m1; m2 = __builtin_amdgcn_fmed3f(q.y, m1, m2);
      m1 = fmaxf(m1, q.y); iq = c ? i : iq; ij = c ? 1 : ij; s1 += __expf(q.y); }
    { bool c = q.z > m1; m2 = __builtin_amdgcn_fmed3f(q.z, m1, m2);
      m1 = fmaxf(m1, q.z); iq = c ? i : iq; ij = c ? 2 : ij; s2 += __expf(q.z); }
    { bool c = q.w > m1; m2 = __builtin_amdgcn_fmed3f(q.w, m1, m2);
      m1 = fmaxf(m1, q.w); iq = c ? i : iq; ij = c ? 3 : ij; s3 += __expf(q.w); }
  };

#pragma unroll
  for (int kb = 0; kb < 3; ++kb) {
    float4 q[4];
    const int i0 = tid + 512 * 4 * kb;
#pragma unroll
    for (int k = 0; k < 4; ++k) q[k] = x4[i0 + 512 * k];
#pragma unroll
    for (int k = 0; k < 4; ++k) consume(q[k], i0 + 512 * k);
  }
  if (tid < TAILQ) {
    float4 q = x4[tid + 512 * 12];
    consume(q, tid + 512 * 12);
  }
  int idx = iq * 4 + ij;  // global element index of per-thread argmax

  double sumd = (double)(s0 + s1) + (double)(s2 + s3);
#pragma unroll
  for (int d = 1; d < 64; d <<= 1) {
    float om1 = __shfl_xor(m1, d, 64);
    float om2 = __shfl_xor(m2, d, 64);
    int oidx = __shfl_xor(idx, d, 64);
    double osum = __shfl_xor(sumd, d, 64);
    sumd += osum;
    float nm2 = fmaxf(fminf(m1, om1), fmaxf(m2, om2));
    bool take = (om1 > m1) || (om1 == m1 && oidx < idx);
    m1 = take ? om1 : m1;
    idx = take ? oidx : idx;
    m2 = nm2;
  }
  if ((tid & 63) == 0) {
    int w = tid >> 6;
    g_m1[w] = m1; g_m2[w] = m2; g_idx[w] = idx; g_sum[w] = sumd;
  }
  __syncthreads();

  const int t = row / B_, b = row % B_;
  const int orow = b * T_ + t;
  if (tid == 0) {
    float M1 = g_m1[0], M2 = g_m2[0]; int I = g_idx[0]; double S = g_sum[0];
#pragma unroll
    for (int w = 1; w < 8; ++w) {
      S += g_sum[w];
      float b1 = g_m1[w], b2 = g_m2[w];
      float nm2 = fmaxf(fminf(M1, b1), fmaxf(M2, b2));
      bool take = (b1 > M1) || (b1 == M1 && g_idx[w] < I);
      if (take) { M1 = b1; I = g_idx[w]; }
      M2 = nm2;
    }
    d_den[orow] = S;
    d_m1[orow] = M1;
    d_i0[orow] = I;
    int tied = (__float_as_uint(M1) == __float_as_uint(M2)) ? 1 : 0;
    d_tied[orow] = tied;
    sh_phase2 = tied | (t == 0 ? 1 : 0);
  }
  __syncthreads();

  // ---------------- phase 2 (rare): exact top-4 re-scan -------------------
  if (sh_phase2) {
    float* sv = (float*)smem;        // [512][4]
    int* si = (int*)(smem + 8192);   // [512][4]
    float tv[4] = {-INFINITY, -INFINITY, -INFINITY, -INFINITY};
    int ti4[4] = {0x7fffffff, 0x7fffffff, 0x7fffffff, 0x7fffffff};
    auto ins = [&](float cv, int ci2) {
#pragma unroll
      for (int k = 0; k < 4; ++k) {
        if (better(cv, ci2, tv[k], ti4[k])) {
          float t0 = tv[k]; int t1 = ti4[k];
          tv[k] = cv; ti4[k] = ci2;
          cv = t0; ci2 = t1;
        }
      }
    };
    for (int i = tid; i < NT4; i += 512) {
      float4 q = x4[i];
      const int gi = 4 * i;
      if (better(q.x, gi + 0, tv[3], ti4[3])) ins(q.x, gi + 0);
      if (better(q.y, gi + 1, tv[3], ti4[3])) ins(q.y, gi + 1);
      if (better(q.z, gi + 2, tv[3], ti4[3])) ins(q.z, gi + 2);
      if (better(q.w, gi + 3, tv[3], ti4[3])) ins(q.w, gi + 3);
    }
#pragma unroll
    for (int k = 0; k < 4; ++k) { sv[tid * 4 + k] = tv[k]; si[tid * 4 + k] = ti4[k]; }
    __syncthreads();
    for (int off = 256; off > 0; off >>= 1) {
      if (tid < off) {
        float a0[4], ov[4]; int a1[4], oi[4];
#pragma unroll
        for (int k = 0; k < 4; ++k) { a0[k] = sv[tid * 4 + k]; a1[k] = si[tid * 4 + k]; }
        int pa = 0, pb = 0;
#pragma unroll
        for (int k = 0; k < 4; ++k) {
          float bv_ = sv[(tid + off) * 4 + pb]; int bi_ = si[(tid + off) * 4 + pb];
          if (better(a0[pa], a1[pa], bv_, bi_)) { ov[k] = a0[pa]; oi[k] = a1[pa]; ++pa; }
          else { ov[k] = bv_; oi[k] = bi_; ++pb; }
        }
#pragma unroll
        for (int k = 0; k < 4; ++k) { sv[tid * 4 + k] = ov[k]; si[tid * 4 + k] = oi[k]; }
      }
      __syncthreads();
    }
    if (tid == 0) {
#pragma unroll
      for (int k = 0; k < 4; ++k) {
        d_t4v[orow * 4 + k] = sv[k];
        d_t4i[orow * 4 + k] = si[k];
      }
    }
    __syncthreads();
  }

  // ---------------- completion handshake (tid0 did ALL global writes) -----
  if (tid == 0) {
    __threadfence();                    // release
    int old = atomicAdd(counter, 1);    // device-scope
    sh_last = (old == NROWS - 1) ? 1 : 0;
  }
  __syncthreads();
  if (!sh_last) return;
  __threadfence();                      // acquire
  __syncthreads();

  // ---------------- beam stage (last block only; wave w = batch w) --------
  double* lp0a = (double*)smem;                          // [8][128]
  double* Sa = (double*)(smem + 8192);                   // [8][128]
  int* ci0a = (int*)(smem + 16384);                      // [8][128]
  unsigned short* seqa = (unsigned short*)(smem + 20480);  // [8][4][128]
  double* scoresa = (double*)(smem + 28672);             // [8][4]
  double* logsa = (double*)(smem + 28928);               // [8][4]
  int* forda = (int*)(smem + 29184);                     // [8][4]

  // deferred f64 log: lp0 = M1 - log(den), 2 rows/thread
  for (int r = tid; r < NROWS; r += 512) {
    lp0a[r] = (double)d_m1[r] - log(d_den[r]);
    ci0a[r] = d_i0[r];
  }
  __syncthreads();

  const int wv = tid >> 6;      // wave id = batch
  const int lane = tid & 63;
  const int bb = wv;
  const int basep = bb * T_;

  bool slA = (lane >= 1) && (d_tied[basep + lane] != 0);
  bool slB = (d_tied[basep + 64 + lane] != 0);
  const unsigned long long mask0 = __ballot(slA);
  const unsigned long long mask1 = __ballot(slB);

  // per-wave inclusive prefix sum of e_t = lp0[t] (e_0 := 0)
  {
    const int t0 = 2 * lane, t1 = 2 * lane + 1;
    double e0 = (t0 >= 1) ? lp0a[basep + t0] : 0.0;
    double e1 = lp0a[basep + t1];
    double pair = e0 + e1, sc = pair;
#pragma unroll
    for (int d = 1; d < 64; d <<= 1) {
      double o = __shfl_up(sc, d, 64);
      if (lane >= d) sc += o;
    }
    Sa[basep + t0] = sc - pair + e0;
    Sa[basep + t1] = sc;
  }

  // parallel fill of fast-step chars (beam-independent)
  for (int t2 = lane + 1; t2 < T_; t2 += 64) {
    bool slow = (t2 < 64) ? ((mask0 >> t2) & 1ull) : ((mask1 >> (t2 - 64)) & 1ull);
    if (!slow) {
      unsigned short c = (unsigned short)ci0a[basep + t2];
      seqa[(bb * 4 + 0) * T_ + t2] = c;
      seqa[(bb * 4 + 1) * T_ + t2] = c;
      seqa[(bb * 4 + 2) * T_ + t2] = c;
      seqa[(bb * 4 + 3) * T_ + t2] = c;
    }
  }
  __syncthreads();

  if (lane == 0) {
    double logs[4], scor[4] = {0.0, 0.0, 0.0, 0.0};
    {
      double lden0 = log(d_den[basep]);
      for (int j = 0; j < 4; ++j)
        logs[j] = (double)d_t4v[basep * 4 + j] - lden0;  // t=0 seed
    }
    int tprev = 0, lastSlow = -1;
    unsigned long long mm = mask0; int phase = 0;
    while (true) {
      if (mm == 0) { if (phase == 0) { mm = mask1; phase = 1; continue; } break; }
      int bpos = __builtin_ctzll(mm); mm &= mm - 1;
      int ts = bpos + (phase ? 64 : 0);

      double add = Sa[basep + ts - 1] - Sa[basep + tprev];
      for (int j = 0; j < 4; ++j) logs[j] += add;

      // tie-exact general step: candidate order = (value-bits desc, beam asc,
      // char asc) == flattened top_k tie rule
      const int row4 = (basep + ts) * 4;
      float v[4]; int ci[4]; double lpk4[4], pk4[4];
      double lden = log(d_den[basep + ts]);
      for (int k = 0; k < 4; ++k) {
        v[k] = d_t4v[row4 + k];
        ci[k] = d_t4i[row4 + k];
        lpk4[k] = (double)v[k] - lden;
        pk4[k] = exp(lpk4[k]);
      }
      int sw[4], sc_[4], sk[4]; int ns = 0; int k = 0;
      while (ns < 4 && k < 4) {
        int k2 = k;
        while (k2 + 1 < 4 &&
               __float_as_uint(v[k2 + 1]) == __float_as_uint(v[k])) ++k2;
        for (int w2 = 0; w2 < 4 && ns < 4; ++w2)
          for (int kk = k; kk <= k2 && ns < 4; ++kk) {
            sw[ns] = w2; sc_[ns] = ci[kk]; sk[ns] = kk; ++ns;
          }
        k = k2 + 1;
      }
      double nl[4];
      for (int j = 0; j < 4; ++j) nl[j] = logs[sw[j]] + lpk4[sk[j]];
      int ord[4] = {0, 1, 2, 3};
      for (int a = 1; a < 4; ++a) {
        int o = ord[a]; int bq = a;
        while (bq > 0 && nl[ord[bq - 1]] < nl[o]) { ord[bq] = ord[bq - 1]; --bq; }
        ord[bq] = o;
      }
      for (int j = 0; j < 4; ++j)
        pch_g[(basep + ts) * 4 + j] =
            ((unsigned)sw[ord[j]] << 16) | (unsigned)sc_[ord[j]];
      double tl[4];
      for (int j = 0; j < 4; ++j) tl[j] = nl[ord[j]];
      for (int j = 0; j < 4; ++j) logs[j] = tl[j];
      if (ts == T_ - 1)
        for (int j = 0; j < 4; ++j) scor[j] = pk4[sk[ord[j]]];
      tprev = ts;
      lastSlow = ts;
    }
    double add = Sa[basep + T_ - 1] - Sa[basep + tprev];
    for (int j = 0; j < 4; ++j) logs[j] += add;
    if (lastSlow != T_ - 1) {
      double pl = exp(lp0a[basep + T_ - 1]);
      for (int j = 0; j < 4; ++j) scor[j] = pl;
    }

    // final stable sort by f32-cast scores, desc
    float sf[4];
    for (int j = 0; j < 4; ++j) sf[j] = (float)scor[j];
    int ford[4] = {0, 1, 2, 3};
    for (int a = 1; a < 4; ++a) {
      int o = ford[a]; int bq = a;
      while (bq > 0 && sf[ford[bq - 1]] < sf[o]) { ford[bq] = ford[bq - 1]; --bq; }
      ford[bq] = o;
    }
    for (int w2 = 0; w2 < 4; ++w2) {
      forda[bb * 4 + w2] = ford[w2];
      scoresa[bb * 4 + w2] = scor[ford[w2]];
      logsa[bb * 4 + w2] = logs[ford[w2]];
    }
  }
  __syncthreads();

  // lanes 0..3: resolve tie-step chars via backpointer walk (descending)
  if (lane < W_) {
    int j = forda[bb * 4 + lane];
    unsigned long long mm = mask1; int phase = 1;
    while (true) {
      if (mm == 0) { if (phase == 1) { mm = mask0; phase = 0; continue; } break; }
      int bpos = 63 - __builtin_clzll(mm); mm &= ~(1ull << bpos);
      int ts = bpos + (phase ? 64 : 0);
      unsigned pc = pch_g[(basep + ts) * 4 + j];
      seqa[(bb * 4 + lane) * T_ + ts] = (unsigned short)(pc & 0xFFFFu);
      j = (int)(pc >> 16);
    }
    seqa[(bb * 4 + lane) * T_ + 0] = (unsigned short)d_t4i[basep * 4 + j];
  }
  __syncthreads();

  // outputs: seqs [B][W][T+1], scores [B][W], logs [B][W]
  for (int e = lane; e < W_ * (T_ + 1); e += 64) {
    int w2 = e / (T_ + 1), p = e % (T_ + 1);
    int c = (p == 0) ? 0 : (int)seqa[(bb * 4 + w2) * T_ + (p - 1)];
    if (c == 1) c = 0;  // EOS -> BLANK
    out[(size_t)(bb * W_ + w2) * (T_ + 1) + p] = (float)c;
  }
  if (lane < W_) {
    out[SEQ_ELEMS + bb * W_ + lane] = (float)scoresa[bb * 4 + lane];
    out[SEQ_ELEMS + B_ * W_ + bb * W_ + lane] = (float)logsa[bb * 4 + lane];
  }
}

// ---------------------------------------------------------------------------
extern "C" void kernel_launch(void* const* d_in, const int* in_sizes, int n_in,
                              void* d_out, int out_size, void* d_ws,
                              size_t ws_size, hipStream_t stream) {
  const float* logits = (const float*)d_in[0];
  // d_in[1] = seq_len (all == T): unused by the reference math.
  char* ws = (char*)d_ws;
  float* out = (float*)d_out;

  // reset the completion counter (graph-capturable async memset)
  hipMemsetAsync(ws + WS_CNT, 0, sizeof(int), stream);

  hipLaunchKernelGGL(fused_kernel, dim3(NROWS), dim3(512), 0, stream,
                     logits, ws, out);
}

// Round 8
// 75.638 us; speedup vs baseline: 1.1307x; 1.1307x over previous
//
#include <hip/hip_runtime.h>
#include <math.h>

#define T_ 128
#define B_ 8
#define C_ 25000
#define W_ 4
#define NROWS (T_ * B_)          // 1024
#define NT4 (C_ / 4)             // 6250 quads/row
#define SEQ_ELEMS (B_ * W_ * (T_ + 1))  // 4128

#define CHUNK_F 6144             // floats per full chunk (24 KB)
#define CHUNK_B (CHUNK_F * 4)    // 24576 B = 24 x 1KB wave-DMA calls
#define CHUNK_Q (CHUNK_F / 4)    // 1536 quads
#define NFULL 4
#define TAIL_F (C_ - NFULL * CHUNK_F)  // 424 floats
#define TAIL_Q (TAIL_F / 4)            // 106 quads (1696 B = 1024 + 672)

// workspace layout (bytes), rows indexed orow = b*T_ + t
#define WS_DEN   0        // [1024] f64  sum(exp(x))
#define WS_M1    8192     // [1024] f32  row max
#define WS_I0    12288    // [1024] i32  argmax (first occurrence)
#define WS_TIED  16384    // [1024] i32  max duplicated (bitwise)
#define WS_T4V   20480    // [1024][4] f32  (phase-2 rows only)
#define WS_T4I   36864    // [1024][4] i32
#define WS_PCH   53248    // [8][128][4] u32 (parent<<16)|char at tie steps
#define WS_CNT   69632    // i32 block-completion counter

// Tie-exact comparator: value desc, index asc (matches lax.top_k tie rule).
__device__ __forceinline__ bool better(float av, int ai, float bv, int bi) {
  return (av > bv) || (av == bv && ai < bi);
}

__device__ __forceinline__ void dma16(const void* g, void* l) {
  __builtin_amdgcn_global_load_lds(
      (const __attribute__((address_space(1))) void*)g,
      (__attribute__((address_space(3))) void*)l, 16, 0, 0);
}

#define WAITCNT(n) asm volatile("s_waitcnt vmcnt(" #n ")" ::: "memory")
#define RAW_BARRIER() asm volatile("s_barrier" ::: "memory")

__global__ __launch_bounds__(512) void fused_kernel(
    const float* __restrict__ logits, char* __restrict__ ws,
    float* __restrict__ out) {
  double* d_den = (double*)(ws + WS_DEN);
  float* d_m1 = (float*)(ws + WS_M1);
  int* d_i0 = (int*)(ws + WS_I0);
  int* d_tied = (int*)(ws + WS_TIED);
  float* d_t4v = (float*)(ws + WS_T4V);
  int* d_t4i = (int*)(ws + WS_T4I);
  unsigned* pch_g = (unsigned*)(ws + WS_PCH);
  int* counter = (int*)(ws + WS_CNT);

  // 2 x 24 KB DMA buffers; phase-2 (16 KB) and beam stage (29.3 KB) overlay
  // this space (temporally disjoint, separated by __syncthreads()).
  __shared__ char smem[2 * CHUNK_B] __attribute__((aligned(16)));
  __shared__ float g_m1[8], g_m2[8];
  __shared__ int g_idx[8];
  __shared__ double g_sum[8];
  __shared__ int sh_phase2, sh_last;

  char* bufA = smem;
  char* bufB = smem + CHUNK_B;

  const int row = blockIdx.x;  // row = t*B + b (input layout [T,B,C])
  const int tid = threadIdx.x;
  const int wv = tid >> 6;     // wave id 0..7
  const int lane = tid & 63;
  const char* rowb = (const char*)logits + (size_t)row * (C_ * 4);
  const float4* __restrict__ x4 = (const float4*)rowb;

  // ---------------- phase 1: DMA-staged streaming row stats ---------------
  float m1 = -INFINITY, m2 = -INFINITY;
  int iq = 0, ij = 0;
  float s0 = 0.f, s1 = 0.f, s2 = 0.f, s3 = 0.f;

  auto consume = [&](const float4 q, int i) {  // i = global quad index
    { bool c = q.x > m1; m2 = __builtin_amdgcn_fmed3f(q.x, m1, m2);
      m1 = fmaxf(m1, q.x); iq = c ? i : iq; ij = c ? 0 : ij; s0 += __expf(q.x); }
    { bool c = q.y > m1; m2 = __builtin_amdgcn_fmed3f(q.y, m1, m2);
      m1 = fmaxf(m1, q.y); iq = c ? i : iq; ij = c ? 1 : ij; s1 += __expf(q.y); }
    { bool c = q.z > m1; m2 = __builtin_amdgcn_fmed3f(q.z, m1, m2);
      m1 = fmaxf(m1, q.z); iq = c ? i : iq; ij = c ? 2 : ij; s2 += __expf(q.z); }
    { bool c = q.w > m1; m2 = __builtin_amdgcn_fmed3f(q.w, m1, m2);
      m1 = fmaxf(m1, q.w); iq = c ? i : iq; ij = c ? 3 : ij; s3 += __expf(q.w); }
  };

  auto issue_chunk = [&](int c, char* buf) {
#pragma unroll
    for (int j = 0; j < 3; ++j) {
      const int off = (wv * 3 + j) * 1024 + lane * 16;
      dma16(rowb + (size_t)c * CHUNK_B + off, buf + off);
    }
  };
  auto reduce_chunk = [&](const char* buf, int c) {
    const float4* b4 = (const float4*)buf;
#pragma unroll
    for (int k = 0; k < 3; ++k) {
      float4 q = b4[tid + 512 * k];
      consume(q, c * CHUNK_Q + tid + 512 * k);
    }
  };

  // prologue: 2 chunks in flight (3 DMA calls per wave each)
  issue_chunk(0, bufA);
  issue_chunk(1, bufB);
  // c=0
  WAITCNT(3); RAW_BARRIER();
  reduce_chunk(bufA, 0);
  RAW_BARRIER();
  issue_chunk(2, bufA);
  // c=1
  WAITCNT(3); RAW_BARRIER();
  reduce_chunk(bufB, 1);
  RAW_BARRIER();
  issue_chunk(3, bufB);
  // c=2
  WAITCNT(3); RAW_BARRIER();
  reduce_chunk(bufA, 2);
  RAW_BARRIER();
  if (wv == 0) {  // tail: 1696 B = 1024 + 672 (42 lanes), into bufA
    dma16(rowb + NFULL * CHUNK_B + lane * 16, bufA + lane * 16);
    if (lane < 42)
      dma16(rowb + NFULL * CHUNK_B + 1024 + lane * 16, bufA + 1024 + lane * 16);
  }
  // c=3
  if (wv == 0) { WAITCNT(2); } else { WAITCNT(0); }
  RAW_BARRIER();
  reduce_chunk(bufB, 3);
  // c=4 (tail)
  WAITCNT(0); RAW_BARRIER();
  if (tid < TAIL_Q) {
    float4 q = ((const float4*)bufA)[tid];
    consume(q, NFULL * CHUNK_Q + tid);
  }

  int idx = iq * 4 + ij;  // global element index of per-thread argmax

  double sumd = (double)(s0 + s1) + (double)(s2 + s3);
#pragma unroll
  for (int d = 1; d < 64; d <<= 1) {
    float om1 = __shfl_xor(m1, d, 64);
    float om2 = __shfl_xor(m2, d, 64);
    int oidx = __shfl_xor(idx, d, 64);
    double osum = __shfl_xor(sumd, d, 64);
    sumd += osum;
    float nm2 = fmaxf(fminf(m1, om1), fmaxf(m2, om2));
    bool take = (om1 > m1) || (om1 == m1 && oidx < idx);
    m1 = take ? om1 : m1;
    idx = take ? oidx : idx;
    m2 = nm2;
  }
  if (lane == 0) {
    g_m1[wv] = m1; g_m2[wv] = m2; g_idx[wv] = idx; g_sum[wv] = sumd;
  }
  __syncthreads();

  const int t = row / B_, b = row % B_;
  const int orow = b * T_ + t;
  if (tid == 0) {
    float M1 = g_m1[0], M2 = g_m2[0]; int I = g_idx[0]; double S = g_sum[0];
#pragma unroll
    for (int w = 1; w < 8; ++w) {
      S += g_sum[w];
      float b1 = g_m1[w], b2 = g_m2[w];
      float nm2 = fmaxf(fminf(M1, b1), fmaxf(M2, b2));
      bool take = (b1 > M1) || (b1 == M1 && g_idx[w] < I);
      if (take) { M1 = b1; I = g_idx[w]; }
      M2 = nm2;
    }
    d_den[orow] = S;
    d_m1[orow] = M1;
    d_i0[orow] = I;
    int tied = (__float_as_uint(M1) == __float_as_uint(M2)) ? 1 : 0;
    d_tied[orow] = tied;
    sh_phase2 = tied | (t == 0 ? 1 : 0);
  }
  __syncthreads();

  // ---------------- phase 2 (rare): exact top-4 re-scan from global -------
  if (sh_phase2) {
    float* sv = (float*)smem;        // [512][4]
    int* si = (int*)(smem + 8192);   // [512][4]
    float tv[4] = {-INFINITY, -INFINITY, -INFINITY, -INFINITY};
    int ti4[4] = {0x7fffffff, 0x7fffffff, 0x7fffffff, 0x7fffffff};
    auto ins = [&](float cv, int ci2) {
#pragma unroll
      for (int k = 0; k < 4; ++k) {
        if (better(cv, ci2, tv[k], ti4[k])) {
          float t0 = tv[k]; int t1 = ti4[k];
          tv[k] = cv; ti4[k] = ci2;
          cv = t0; ci2 = t1;
        }
      }
    };
    for (int i = tid; i < NT4; i += 512) {
      float4 q = x4[i];
      const int gi = 4 * i;
      if (better(q.x, gi + 0, tv[3], ti4[3])) ins(q.x, gi + 0);
      if (better(q.y, gi + 1, tv[3], ti4[3])) ins(q.y, gi + 1);
      if (better(q.z, gi + 2, tv[3], ti4[3])) ins(q.z, gi + 2);
      if (better(q.w, gi + 3, tv[3], ti4[3])) ins(q.w, gi + 3);
    }
#pragma unroll
    for (int k = 0; k < 4; ++k) { sv[tid * 4 + k] = tv[k]; si[tid * 4 + k] = ti4[k]; }
    __syncthreads();
    for (int off = 256; off > 0; off >>= 1) {
      if (tid < off) {
        float a0[4], ov[4]; int a1[4], oi[4];
#pragma unroll
        for (int k = 0; k < 4; ++k) { a0[k] = sv[tid * 4 + k]; a1[k] = si[tid * 4 + k]; }
        int pa = 0, pb = 0;
#pragma unroll
        for (int k = 0; k < 4; ++k) {
          float bv_ = sv[(tid + off) * 4 + pb]; int bi_ = si[(tid + off) * 4 + pb];
          if (better(a0[pa], a1[pa], bv_, bi_)) { ov[k] = a0[pa]; oi[k] = a1[pa]; ++pa; }
          else { ov[k] = bv_; oi[k] = bi_; ++pb; }
        }
#pragma unroll
        for (int k = 0; k < 4; ++k) { sv[tid * 4 + k] = ov[k]; si[tid * 4 + k] = oi[k]; }
      }
      __syncthreads();
    }
    if (tid == 0) {
#pragma unroll
      for (int k = 0; k < 4; ++k) {
        d_t4v[orow * 4 + k] = sv[k];
        d_t4i[orow * 4 + k] = si[k];
      }
    }
    __syncthreads();
  }

  // ---------------- completion handshake (tid0 did ALL global writes) -----
  if (tid == 0) {
    __threadfence();                    // release
    int old = atomicAdd(counter, 1);    // device-scope
    sh_last = (old == NROWS - 1) ? 1 : 0;
  }
  __syncthreads();
  if (!sh_last) return;
  __threadfence();                      // acquire
  __syncthreads();

  // ---------------- beam stage (last block only; wave w = batch w) --------
  double* lp0a = (double*)smem;                          // [8][128]
  double* Sa = (double*)(smem + 8192);                   // [8][128]
  int* ci0a = (int*)(smem + 16384);                      // [8][128]
  unsigned short* seqa = (unsigned short*)(smem + 20480);  // [8][4][128]
  double* scoresa = (double*)(smem + 28672);             // [8][4]
  double* logsa = (double*)(smem + 28928);               // [8][4]
  int* forda = (int*)(smem + 29184);                     // [8][4]

  // deferred f64 log: lp0 = M1 - log(den), 2 rows/thread
  for (int r = tid; r < NROWS; r += 512) {
    lp0a[r] = (double)d_m1[r] - log(d_den[r]);
    ci0a[r] = d_i0[r];
  }
  __syncthreads();

  const int bb = wv;
  const int basep = bb * T_;

  bool slA = (lane >= 1) && (d_tied[basep + lane] != 0);
  bool slB = (d_tied[basep + 64 + lane] != 0);
  const unsigned long long mask0 = __ballot(slA);
  const unsigned long long mask1 = __ballot(slB);

  // per-wave inclusive prefix sum of e_t = lp0[t] (e_0 := 0)
  {
    const int t0 = 2 * lane, t1 = 2 * lane + 1;
    double e0 = (t0 >= 1) ? lp0a[basep + t0] : 0.0;
    double e1 = lp0a[basep + t1];
    double pair = e0 + e1, sc = pair;
#pragma unroll
    for (int d = 1; d < 64; d <<= 1) {
      double o = __shfl_up(sc, d, 64);
      if (lane >= d) sc += o;
    }
    Sa[basep + t0] = sc - pair + e0;
    Sa[basep + t1] = sc;
  }

  // parallel fill of fast-step chars (beam-independent)
  for (int t2 = lane + 1; t2 < T_; t2 += 64) {
    bool slow = (t2 < 64) ? ((mask0 >> t2) & 1ull) : ((mask1 >> (t2 - 64)) & 1ull);
    if (!slow) {
      unsigned short c = (unsigned short)ci0a[basep + t2];
      seqa[(bb * 4 + 0) * T_ + t2] = c;
      seqa[(bb * 4 + 1) * T_ + t2] = c;
      seqa[(bb * 4 + 2) * T_ + t2] = c;
      seqa[(bb * 4 + 3) * T_ + t2] = c;
    }
  }
  __syncthreads();

  if (lane == 0) {
    double logs[4], scor[4] = {0.0, 0.0, 0.0, 0.0};
    {
      double lden0 = log(d_den[basep]);
      for (int j = 0; j < 4; ++j)
        logs[j] = (double)d_t4v[basep * 4 + j] - lden0;  // t=0 seed
    }
    int tprev = 0, lastSlow = -1;
    unsigned long long mm = mask0; int phase = 0;
    while (true) {
      if (mm == 0) { if (phase == 0) { mm = mask1; phase = 1; continue; } break; }
      int bpos = __builtin_ctzll(mm); mm &= mm - 1;
      int ts = bpos + (phase ? 64 : 0);

      double add = Sa[basep + ts - 1] - Sa[basep + tprev];
      for (int j = 0; j < 4; ++j) logs[j] += add;

      // tie-exact general step: candidate order = (value-bits desc, beam asc,
      // char asc) == flattened top_k tie rule
      const int row4 = (basep + ts) * 4;
      float v[4]; int ci[4]; double lpk4[4], pk4[4];
      double lden = log(d_den[basep + ts]);
      for (int k = 0; k < 4; ++k) {
        v[k] = d_t4v[row4 + k];
        ci[k] = d_t4i[row4 + k];
        lpk4[k] = (double)v[k] - lden;
        pk4[k] = exp(lpk4[k]);
      }
      int sw[4], sc_[4], sk[4]; int ns = 0; int k = 0;
      while (ns < 4 && k < 4) {
        int k2 = k;
        while (k2 + 1 < 4 &&
               __float_as_uint(v[k2 + 1]) == __float_as_uint(v[k])) ++k2;
        for (int w2 = 0; w2 < 4 && ns < 4; ++w2)
          for (int kk = k; kk <= k2 && ns < 4; ++kk) {
            sw[ns] = w2; sc_[ns] = ci[kk]; sk[ns] = kk; ++ns;
          }
        k = k2 + 1;
      }
      double nl[4];
      for (int j = 0; j < 4; ++j) nl[j] = logs[sw[j]] + lpk4[sk[j]];
      int ord[4] = {0, 1, 2, 3};
      for (int a = 1; a < 4; ++a) {
        int o = ord[a]; int bq = a;
        while (bq > 0 && nl[ord[bq - 1]] < nl[o]) { ord[bq] = ord[bq - 1]; --bq; }
        ord[bq] = o;
      }
      for (int j = 0; j < 4; ++j)
        pch_g[(basep + ts) * 4 + j] =
            ((unsigned)sw[ord[j]] << 16) | (unsigned)sc_[ord[j]];
      double tl[4];
      for (int j = 0; j < 4; ++j) tl[j] = nl[ord[j]];
      for (int j = 0; j < 4; ++j) logs[j] = tl[j];
      if (ts == T_ - 1)
        for (int j = 0; j < 4; ++j) scor[j] = pk4[sk[ord[j]]];
      tprev = ts;
      lastSlow = ts;
    }
    double add = Sa[basep + T_ - 1] - Sa[basep + tprev];
    for (int j = 0; j < 4; ++j) logs[j] += add;
    if (lastSlow != T_ - 1) {
      double pl = exp(lp0a[basep + T_ - 1]);
      for (int j = 0; j < 4; ++j) scor[j] = pl;
    }

    // final stable sort by f32-cast scores, desc
    float sf[4];
    for (int j = 0; j < 4; ++j) sf[j] = (float)scor[j];
    int ford[4] = {0, 1, 2, 3};
    for (int a = 1; a < 4; ++a) {
      int o = ford[a]; int bq = a;
      while (bq > 0 && sf[ford[bq - 1]] < sf[o]) { ford[bq] = ford[bq - 1]; --bq; }
      ford[bq] = o;
    }
    for (int w2 = 0; w2 < 4; ++w2) {
      forda[bb * 4 + w2] = ford[w2];
      scoresa[bb * 4 + w2] = scor[ford[w2]];
      logsa[bb * 4 + w2] = logs[ford[w2]];
    }
  }
  __syncthreads();

  // lanes 0..3: resolve tie-step chars via backpointer walk (descending)
  if (lane < W_) {
    int j = forda[bb * 4 + lane];
    unsigned long long mm = mask1; int phase = 1;
    while (true) {
      if (mm == 0) { if (phase == 1) { mm = mask0; phase = 0; continue; } break; }
      int bpos = 63 - __builtin_clzll(mm); mm &= ~(1ull << bpos);
      int ts = bpos + (phase ? 64 : 0);
      unsigned pc = pch_g[(basep + ts) * 4 + j];
      seqa[(bb * 4 + lane) * T_ + ts] = (unsigned short)(pc & 0xFFFFu);
      j = (int)(pc >> 16);
    }
    seqa[(bb * 4 + lane) * T_ + 0] = (unsigned short)d_t4i[basep * 4 + j];
  }
  __syncthreads();

  // outputs: seqs [B][W][T+1], scores [B][W], logs [B][W]
  for (int e = lane; e < W_ * (T_ + 1); e += 64) {
    int w2 = e / (T_ + 1), p = e % (T_ + 1);
    int c = (p == 0) ? 0 : (int)seqa[(bb * 4 + w2) * T_ + (p - 1)];
    if (c == 1) c = 0;  // EOS -> BLANK
    out[(size_t)(bb * W_ + w2) * (T_ + 1) + p] = (float)c;
  }
  if (lane < W_) {
    out[SEQ_ELEMS + bb * W_ + lane] = (float)scoresa[bb * 4 + lane];
    out[SEQ_ELEMS + B_ * W_ + bb * W_ + lane] = (float)logsa[bb * 4 + lane];
  }
}

// ---------------------------------------------------------------------------
extern "C" void kernel_launch(void* const* d_in, const int* in_sizes, int n_in,
                              void* d_out, int out_size, void* d_ws,
                              size_t ws_size, hipStream_t stream) {
  const float* logits = (const float*)d_in[0];
  // d_in[1] = seq_len (all == T): unused by the reference math.
  char* ws = (char*)d_ws;
  float* out = (float*)d_out;

  // reset the completion counter (graph-capturable async memset)
  hipMemsetAsync(ws + WS_CNT, 0, sizeof(int), stream);

  hipLaunchKernelGGL(fused_kernel, dim3(NROWS), dim3(512), 0, stream,
                     logits, ws, out);
}

// Round 9
// 42.882 us; speedup vs baseline: 1.9944x; 1.7639x over previous
//
#include <hip/hip_runtime.h>
#include <math.h>

#define T_ 128
#define B_ 8
#define C_ 25000
#define W_ 4
#define NROWS (T_ * B_)   // 1024
#define NT4 (C_ / 4)      // 6250 quads/row; 6250 = 512*12 + 106
#define TAILQ (NT4 - 512 * 12)  // 106
#define SEQ_ELEMS (B_ * W_ * (T_ + 1))  // 4128

// Tie-exact comparator: value desc, index asc (matches lax.top_k tie rule).
__device__ __forceinline__ bool better(float av, int ai, float bv, int bi) {
  return (av > bv) || (av == bv && ai < bi);
}

// ---------------------------------------------------------------------------
// Kernel A: per row (t,b): argmax (value,index, first occurrence), second-max
// VALUE (duplicate-max detection), den = sum(__expf(x)) (no max subtraction:
// per-row constant rescale; |x|<~6 so f32-safe). NO f64 transcendentals here
// (they inflate whole-kernel VGPR); beam_sim computes lp = v - log(den).
// 512 threads, __launch_bounds__(512,8) caps VGPR at 64 -> 4 blocks/CU ->
// 32 waves/CU, one residency round for the 1024-block grid. Loads are
// double-buffered across batches (3 float4 in flight during each consume).
// Phase 2 (t==0 or tied rows, rare): exact top-4 re-scan from L2/L3.
// ---------------------------------------------------------------------------
__global__ __launch_bounds__(512, 8) void rowstats(
    const float* __restrict__ logits,
    double* __restrict__ d_den, float* __restrict__ d_m1,
    int* __restrict__ d_i0, int* __restrict__ d_tied,
    float* __restrict__ d_t4v, int* __restrict__ d_t4i) {
  const int row = blockIdx.x;  // row = t*B + b (input layout [T,B,C])
  const float4* __restrict__ x4 =
      reinterpret_cast<const float4*>(logits + (size_t)row * C_);
  const int tid = threadIdx.x;

  float m1 = -INFINITY, m2 = -INFINITY;
  int iq = 0, ij = 0;
  float s0 = 0.f, s1 = 0.f, s2 = 0.f, s3 = 0.f;

  auto consume = [&](const float4 q, int i) {  // i = quad index
    { bool c = q.x > m1; m2 = __builtin_amdgcn_fmed3f(q.x, m1, m2);
      m1 = fmaxf(m1, q.x); iq = c ? i : iq; ij = c ? 0 : ij; s0 += __expf(q.x); }
    { bool c = q.y > m1; m2 = __builtin_amdgcn_fmed3f(q.y, m1, m2);
      m1 = fmaxf(m1, q.y); iq = c ? i : iq; ij = c ? 1 : ij; s1 += __expf(q.y); }
    { bool c = q.z > m1; m2 = __builtin_amdgcn_fmed3f(q.z, m1, m2);
      m1 = fmaxf(m1, q.z); iq = c ? i : iq; ij = c ? 2 : ij; s2 += __expf(q.z); }
    { bool c = q.w > m1; m2 = __builtin_amdgcn_fmed3f(q.w, m1, m2);
      m1 = fmaxf(m1, q.w); iq = c ? i : iq; ij = c ? 3 : ij; s3 += __expf(q.w); }
  };

  // ---- phase 1: software-pipelined stream (batches of 3 float4) ----------
  {
    float4 qa[3], qb[3];
#pragma unroll
    for (int k = 0; k < 3; ++k) qa[k] = x4[tid + 512 * k];
#pragma unroll
    for (int bch = 0; bch < 4; ++bch) {
      if (bch < 3) {
#pragma unroll
        for (int k = 0; k < 3; ++k) qb[k] = x4[tid + 512 * (3 * (bch + 1) + k)];
      } else if (tid < TAILQ) {
        qb[0] = x4[tid + 512 * 12];
      }
#pragma unroll
      for (int k = 0; k < 3; ++k) consume(qa[k], tid + 512 * (3 * bch + k));
#pragma unroll
      for (int k = 0; k < 3; ++k) qa[k] = qb[k];
    }
    if (tid < TAILQ) consume(qa[0], tid + 512 * 12);
  }

  int idx = iq * 4 + ij;  // global element index of per-thread argmax

  // wave butterfly reduce (no LDS, no syncs)
  double sumd = (double)(s0 + s1) + (double)(s2 + s3);
#pragma unroll
  for (int d = 1; d < 64; d <<= 1) {
    float om1 = __shfl_xor(m1, d, 64);
    float om2 = __shfl_xor(m2, d, 64);
    int oidx = __shfl_xor(idx, d, 64);
    double osum = __shfl_xor(sumd, d, 64);
    sumd += osum;
    float nm2 = fmaxf(fminf(m1, om1), fmaxf(m2, om2));
    bool take = (om1 > m1) || (om1 == m1 && oidx < idx);
    m1 = take ? om1 : m1;
    idx = take ? oidx : idx;
    m2 = nm2;
  }

  __shared__ float g_m1[8], g_m2[8];
  __shared__ int g_idx[8];
  __shared__ double g_sum[8];
  __shared__ int sh_phase2;
  if ((tid & 63) == 0) {
    int w = tid >> 6;
    g_m1[w] = m1; g_m2[w] = m2; g_idx[w] = idx; g_sum[w] = sumd;
  }
  __syncthreads();

  const int t = row / B_, b = row % B_;
  const int orow = b * T_ + t;  // transposed layout for beam_sim
  if (tid == 0) {
    float M1 = g_m1[0], M2 = g_m2[0]; int I = g_idx[0]; double S = g_sum[0];
#pragma unroll
    for (int w = 1; w < 8; ++w) {
      S += g_sum[w];
      float b1 = g_m1[w], b2 = g_m2[w];
      float nm2 = fmaxf(fminf(M1, b1), fmaxf(M2, b2));
      bool take = (b1 > M1) || (b1 == M1 && g_idx[w] < I);
      if (take) { M1 = b1; I = g_idx[w]; }
      M2 = nm2;
    }
    d_den[orow] = S;
    d_m1[orow] = M1;
    d_i0[orow] = I;
    int tied = (__float_as_uint(M1) == __float_as_uint(M2)) ? 1 : 0;
    d_tied[orow] = tied;
    sh_phase2 = tied | (t == 0 ? 1 : 0);
  }
  __syncthreads();

  if (!sh_phase2) return;

  // ---- phase 2 (rare): exact top-4 (value,index), row re-scan (L2-warm) ----
  float tv[4] = {-INFINITY, -INFINITY, -INFINITY, -INFINITY};
  int ti4[4] = {0x7fffffff, 0x7fffffff, 0x7fffffff, 0x7fffffff};
  auto ins = [&](float cv, int ci2) {
#pragma unroll
    for (int k = 0; k < 4; ++k) {
      if (better(cv, ci2, tv[k], ti4[k])) {
        float t0 = tv[k]; int t1 = ti4[k];
        tv[k] = cv; ti4[k] = ci2;
        cv = t0; ci2 = t1;
      }
    }
  };
  for (int i = tid; i < NT4; i += 512) {
    float4 q = x4[i];
    const int gi = 4 * i;
    if (better(q.x, gi + 0, tv[3], ti4[3])) ins(q.x, gi + 0);
    if (better(q.y, gi + 1, tv[3], ti4[3])) ins(q.y, gi + 1);
    if (better(q.z, gi + 2, tv[3], ti4[3])) ins(q.z, gi + 2);
    if (better(q.w, gi + 3, tv[3], ti4[3])) ins(q.w, gi + 3);
  }

  __shared__ float sv[512 * 4];
  __shared__ int si[512 * 4];
#pragma unroll
  for (int k = 0; k < 4; ++k) { sv[tid * 4 + k] = tv[k]; si[tid * 4 + k] = ti4[k]; }
  __syncthreads();

  for (int off = 256; off > 0; off >>= 1) {
    if (tid < off) {
      float a0[4], ov[4]; int a1[4], oi[4];
#pragma unroll
      for (int k = 0; k < 4; ++k) { a0[k] = sv[tid * 4 + k]; a1[k] = si[tid * 4 + k]; }
      int pa = 0, pb = 0;
#pragma unroll
      for (int k = 0; k < 4; ++k) {
        float bv_ = sv[(tid + off) * 4 + pb]; int bi_ = si[(tid + off) * 4 + pb];
        if (better(a0[pa], a1[pa], bv_, bi_)) { ov[k] = a0[pa]; oi[k] = a1[pa]; ++pa; }
        else { ov[k] = bv_; oi[k] = bi_; ++pb; }
      }
#pragma unroll
      for (int k = 0; k < 4; ++k) { sv[tid * 4 + k] = ov[k]; si[tid * 4 + k] = oi[k]; }
    }
    __syncthreads();
  }

  if (tid == 0) {
#pragma unroll
    for (int k = 0; k < 4; ++k) {
      d_t4v[orow * 4 + k] = sv[k];
      d_t4i[orow * 4 + k] = si[k];
    }
  }
}

// ---------------------------------------------------------------------------
// Kernel B: beam recursion per batch, one wave per block. Identical control
// flow to the r5/r6-passing version; lp/p values computed on the fly from
// (m1, den, t4v) exactly as in the r7/r8-passing beam stage (bit-identical
// expressions: lp = (double)f32 - log(den)).
// ---------------------------------------------------------------------------
__global__ __launch_bounds__(64) void beam_sim(
    const double* __restrict__ d_den, const float* __restrict__ d_m1,
    const int* __restrict__ d_i0, const int* __restrict__ d_tied,
    const float* __restrict__ d_t4v, const int* __restrict__ d_t4i,
    float* __restrict__ out) {
  const int b = blockIdx.x;
  const int tid = threadIdx.x;  // 0..63

  __shared__ double lp0[T_];
  __shared__ int ci0[T_], tiedL[T_];
  __shared__ double S[T_];
  __shared__ int Pst[T_][4], Chst[T_][4];  // only written at tie steps
  __shared__ int seq[W_][T_];
  __shared__ double sh_scores[W_], sh_logs[W_];
  __shared__ int sh_ford[W_];

  const int base = b * T_;
  for (int e = tid; e < T_; e += 64) {
    lp0[e] = (double)d_m1[base + e] - log(d_den[base + e]);
    ci0[e] = d_i0[base + e];
    tiedL[e] = d_tied[base + e];
  }
  __syncthreads();

  // tie masks (t=0 excluded: seed logic always uses full top-4 there)
  bool slA = (tid >= 1) && (tiedL[tid] != 0);
  bool slB = (tiedL[tid + 64] != 0);
  const unsigned long long mask0 = __ballot(slA);
  const unsigned long long mask1 = __ballot(slB);

  // wave-parallel inclusive prefix sum of e_t = lp0[t] (e_0 := 0)
  {
    const int t0 = 2 * tid, t1 = 2 * tid + 1;
    double e0 = (t0 >= 1) ? lp0[t0] : 0.0;
    double e1 = lp0[t1];
    double pair = e0 + e1, sc = pair;
#pragma unroll
    for (int d = 1; d < 64; d <<= 1) {
      double o = __shfl_up(sc, d, 64);
      if (tid >= d) sc += o;
    }
    S[t0] = sc - pair + e0;
    S[t1] = sc;
  }

  // parallel fill of fast-step chars (beam-independent: always ci0[t])
  for (int t = tid + 1; t < T_; t += 64) {
    bool slow = (t < 64) ? ((mask0 >> t) & 1ull) : ((mask1 >> (t - 64)) & 1ull);
    if (!slow) {
      int c = ci0[t];
      seq[0][t] = c; seq[1][t] = c; seq[2][t] = c; seq[3][t] = c;
    }
  }
  __syncthreads();

  if (tid == 0) {
    double logs[4], scor[4] = {0.0, 0.0, 0.0, 0.0};
    {
      double lden0 = log(d_den[base]);
      for (int j = 0; j < 4; ++j)
        logs[j] = (double)d_t4v[base * 4 + j] - lden0;  // t=0 seed
    }
    int tprev = 0, lastSlow = -1;
    unsigned long long mm = mask0; int phase = 0;
    while (true) {
      if (mm == 0) { if (phase == 0) { mm = mask1; phase = 1; continue; } break; }
      int bpos = __builtin_ctzll(mm); mm &= mm - 1;
      int ts = bpos + (phase ? 64 : 0);

      double add = S[ts - 1] - S[tprev];
      for (int j = 0; j < 4; ++j) logs[j] += add;

      // tie-exact general step: candidate order = (value-bits desc, beam asc,
      // char asc) == flattened top_k tie rule
      const int row4 = (base + ts) * 4;
      float v[4]; int ci[4]; double lpk4[4], pk4[4];
      double lden = log(d_den[base + ts]);
      for (int k = 0; k < 4; ++k) {
        v[k] = d_t4v[row4 + k];
        ci[k] = d_t4i[row4 + k];
        lpk4[k] = (double)v[k] - lden;
        pk4[k] = exp(lpk4[k]);
      }
      int sw[4], sc_[4], sk[4]; int ns = 0; int k = 0;
      while (ns < 4 && k < 4) {
        int k2 = k;
        while (k2 + 1 < 4 &&
               __float_as_uint(v[k2 + 1]) == __float_as_uint(v[k])) ++k2;
        for (int w2 = 0; w2 < 4 && ns < 4; ++w2)
          for (int kk = k; kk <= k2 && ns < 4; ++kk) {
            sw[ns] = w2; sc_[ns] = ci[kk]; sk[ns] = kk; ++ns;
          }
        k = k2 + 1;
      }
      double nl[4];
      for (int j = 0; j < 4; ++j) nl[j] = logs[sw[j]] + lpk4[sk[j]];
      int ord[4] = {0, 1, 2, 3};
      for (int a = 1; a < 4; ++a) {
        int o = ord[a]; int bq = a;
        while (bq > 0 && nl[ord[bq - 1]] < nl[o]) { ord[bq] = ord[bq - 1]; --bq; }
        ord[bq] = o;
      }
      for (int j = 0; j < 4; ++j) {
        Pst[ts][j] = sw[ord[j]];
        Chst[ts][j] = sc_[ord[j]];
      }
      double tl[4];
      for (int j = 0; j < 4; ++j) tl[j] = nl[ord[j]];
      for (int j = 0; j < 4; ++j) logs[j] = tl[j];
      if (ts == T_ - 1)
        for (int j = 0; j < 4; ++j) scor[j] = pk4[sk[ord[j]]];
      tprev = ts;
      lastSlow = ts;
    }
    double add = S[T_ - 1] - S[tprev];
    for (int j = 0; j < 4; ++j) logs[j] += add;
    if (lastSlow != T_ - 1) {
      double pl = exp(lp0[T_ - 1]);
      for (int j = 0; j < 4; ++j) scor[j] = pl;
    }

    // final stable sort by f32-cast scores, desc (matches argsort(-scores))
    float sf[4];
    for (int j = 0; j < 4; ++j) sf[j] = (float)scor[j];
    int ford[4] = {0, 1, 2, 3};
    for (int a = 1; a < 4; ++a) {
      int o = ford[a]; int bq = a;
      while (bq > 0 && sf[ford[bq - 1]] < sf[o]) { ford[bq] = ford[bq - 1]; --bq; }
      ford[bq] = o;
    }
    for (int w2 = 0; w2 < 4; ++w2) {
      sh_ford[w2] = ford[w2];
      sh_scores[w2] = scor[ford[w2]];
      sh_logs[w2] = logs[ford[w2]];
    }
  }
  __syncthreads();

  // lanes 0..3: walk tie steps (descending) to resolve beam-dependent chars
  if (tid < W_) {
    int j = sh_ford[tid];
    unsigned long long mm = mask1; int phase = 1;
    while (true) {
      if (mm == 0) { if (phase == 1) { mm = mask0; phase = 0; continue; } break; }
      int bpos = 63 - __builtin_clzll(mm); mm &= ~(1ull << bpos);
      int ts = bpos + (phase ? 64 : 0);
      seq[tid][ts] = Chst[ts][j];
      j = Pst[ts][j];
    }
    seq[tid][0] = d_t4i[base * 4 + j];  // t=0 char of surviving seed index
  }
  __syncthreads();

  // outputs: seqs [B][W][T+1], scores [B][W], logs [B][W]
  for (int e = tid; e < W_ * (T_ + 1); e += 64) {
    int w2 = e / (T_ + 1), p = e % (T_ + 1);
    int c = (p == 0) ? 0 : seq[w2][p - 1];
    if (c == 1) c = 0;  // EOS -> BLANK
    out[(size_t)(b * W_ + w2) * (T_ + 1) + p] = (float)c;
  }
  if (tid < W_) {
    out[SEQ_ELEMS + b * W_ + tid] = (float)sh_scores[tid];
    out[SEQ_ELEMS + B_ * W_ + b * W_ + tid] = (float)sh_logs[tid];
  }
}

// ---------------------------------------------------------------------------
extern "C" void kernel_launch(void* const* d_in, const int* in_sizes, int n_in,
                              void* d_out, int out_size, void* d_ws,
                              size_t ws_size, hipStream_t stream) {
  const float* logits = (const float*)d_in[0];
  // d_in[1] = seq_len (all == T): unused by the reference math.

  char* ws = (char*)d_ws;
  double* d_den = (double*)(ws + 0);        // 1024 f64 =  8 KB
  float* d_m1 = (float*)(ws + 8192);        // 1024 f32 =  4 KB
  int* d_i0 = (int*)(ws + 12288);           // 1024 i32 =  4 KB
  int* d_tied = (int*)(ws + 16384);         // 1024 i32 =  4 KB
  float* d_t4v = (float*)(ws + 20480);      // 4096 f32 = 16 KB
  int* d_t4i = (int*)(ws + 36864);          // 4096 i32 = 16 KB
  float* out = (float*)d_out;

  hipLaunchKernelGGL(rowstats, dim3(NROWS), dim3(512), 0, stream,
                     logits, d_den, d_m1, d_i0, d_tied, d_t4v, d_t4i);
  hipLaunchKernelGGL(beam_sim, dim3(B_), dim3(64), 0, stream,
                     d_den, d_m1, d_i0, d_tied, d_t4v, d_t4i, out);
}